// Round 1
// baseline (68914.423 us; speedup 1.0000x reference)
//
#include <hip/hip_runtime.h>

typedef _Float16 f16;
typedef _Float16 f16x2 __attribute__((ext_vector_type(2)));
typedef _Float16 f16x8 __attribute__((ext_vector_type(8)));
typedef float    f32x4 __attribute__((ext_vector_type(4)));

// ---------------- static device scratch (avoids ws_size assumptions) --------
__device__ f16   g_Xpad [64u*1028u*512u];   // conv1 input (B,T+4,512): ch0-255 coarse, 256-511 fine(final)
__device__ f16   g_fseqA[64u*1024u*256u];   // fine sequence ping
__device__ f16   g_fseqB[64u*1024u*256u];   // fine sequence pong
__device__ float g_xg32 [64u*1024u*1024u];  // per-f-layer input projection, permuted gate order, fp32
__device__ f16   g_c2in [64u*1026u*256u];   // conv2 input (B,T+2,256), padded
__device__ f16   g_c3in [64u*1024u*128u];   // conv3 input (B,T,128)
__device__ f16   g_whhT2[5u*262144u];       // [L][k2][g'][2] fp16, permuted gate rows
__device__ f16   g_wihB [3u*262144u];       // [l][g'][k] fp16, permuted gate rows
__device__ float g_biasP[3*1024];           // permuted bih+bhh for f1..f3
__device__ f16   g_B1   [256u*2560u];       // conv1 weight as GEMM B [oc][r*512+ic]
__device__ f16   g_B2   [128u*768u];        // conv2 weight as GEMM B [oc][r*256+ic]
__device__ float g_xg0  [2*64*1024];        // static xg for coarse/f0, permuted
__device__ float g_cat512[64*512];          // [h, le]
__device__ float g_h    [64*256];
__device__ float g_feats[64*512];           // [coarse.mean, fine.mean]
__device__ float g_osc  [64*1024];
__device__ float g_smean[1024];
__device__ float g_cpar [64*4];             // raw cp sigmoid outputs
__device__ float g_enh  [64*1024];

// ---------------- helpers ---------------------------------------------------
__device__ inline float fdot2f(f16x2 a, f16x2 b, float c) {
#if __has_builtin(__builtin_amdgcn_fdot2)
  return __builtin_amdgcn_fdot2(a, b, c, false);
#else
  return c + (float)a[0]*(float)b[0] + (float)a[1]*(float)b[1];
#endif
}
__device__ inline float sigm_fast(float x) { return 1.0f / (1.0f + __expf(-x)); }
__device__ inline float tanh_fast(float x) { float e = __expf(2.0f*x); return 1.0f - 2.0f/(e + 1.0f); }
__device__ inline float lrelu(float x) { return x < 0.0f ? 0.2f*x : x; }
__device__ inline void expand8(f16x8 v, f16x2* dst) {
  dst[0] = __builtin_shufflevector(v, v, 0, 1);
  dst[1] = __builtin_shufflevector(v, v, 2, 3);
  dst[2] = __builtin_shufflevector(v, v, 4, 5);
  dst[3] = __builtin_shufflevector(v, v, 6, 7);
}

// ---------------- weight prep ----------------------------------------------
// permuted gate order: g' = j*4+q  <->  g = q*256+j   (q: 0=i,1=f,2=g,3=o)
__global__ void __launch_bounds__(256) k_prep_whh(const float* cw, const float* f0w, const float* fw) {
  int bid = blockIdx.x;               // 5*1024
  int L = bid >> 10, gp = bid & 1023, k = threadIdx.x;
  const float* src = (L == 0) ? cw : (L == 1) ? f0w : (fw + (size_t)(L-2)*262144u);
  int j = gp >> 2, q = gp & 3, g = q*256 + j;
  float v = src[(size_t)g*256 + k];
  g_whhT2[(size_t)L*262144u + (size_t)(k>>1)*2048u + (size_t)gp*2u + (k&1)] = (f16)v;
}
__global__ void __launch_bounds__(256) k_prep_wih(const float* fwih, const float* fbih, const float* fbhh) {
  int bid = blockIdx.x;               // 3*1024
  int L = bid >> 10, gp = bid & 1023, k = threadIdx.x;
  int j = gp >> 2, q = gp & 3, g = q*256 + j;
  g_wihB[(size_t)L*262144u + (size_t)gp*256u + k] = (f16)fwih[(size_t)L*262144u + (size_t)g*256u + k];
  if (k == 0) g_biasP[L*1024 + gp] = fbih[L*1024 + g] + fbhh[L*1024 + g];
}
__global__ void __launch_bounds__(256) k_prep_c1(const float* w) {
  int idx = blockIdx.x*256 + threadIdx.x;        // 655360
  int oc = idx / 2560, rem = idx % 2560, r = rem / 512, ic = rem % 512;
  g_B1[idx] = (f16)w[(size_t)oc*2560 + (size_t)ic*5 + r];
}
__global__ void __launch_bounds__(256) k_prep_c2(const float* w) {
  int idx = blockIdx.x*256 + threadIdx.x;        // 98304
  int oc = idx / 768, rem = idx % 768, r = rem / 256, ic = rem % 256;
  g_B2[idx] = (f16)w[(size_t)oc*768 + (size_t)ic*3 + r];
}
__global__ void __launch_bounds__(256) k_zero() {
  int idx = blockIdx.x*256 + threadIdx.x;        // 163840
  if (idx < 131072) {   // Xpad pad rows 0,1,1026,1027
    int b = idx >> 11, rem = idx & 2047, rr = rem >> 9, c = rem & 511;
    int row = (rr < 2) ? rr : 1024 + rr;
    g_Xpad[(size_t)b*526336u + (size_t)row*512u + c] = (f16)0.0f;
  } else {              // c2in pad rows 0, 1025
    int i2 = idx - 131072;
    int b = i2 >> 9, rem = i2 & 511, rr = rem >> 8, c = rem & 255;
    int row = rr ? 1025 : 0;
    g_c2in[(size_t)b*262656u + (size_t)row*256u + c] = (f16)0.0f;
  }
}

// ---------------- small front-end ops ---------------------------------------
__global__ void __launch_bounds__(256) k_setup1(const float* z, const int* labels, const float* emb,
                                                const float* npw, const float* npb,
                                                const float* lg, const float* lb) {
  __shared__ float x[384];
  __shared__ float s1[256], s2[256];
  int b = blockIdx.x, tid = threadIdx.x;
  int lab = labels[b];
  for (int i = tid; i < 384; i += 256)
    x[i] = (i < 128) ? z[b*128 + i] : emb[lab*256 + (i - 128)];
  __syncthreads();
  float acc = npb[tid];
  for (int k = 0; k < 384; ++k) acc += npw[tid*384 + k]*x[k];
  s1[tid] = acc; s2[tid] = acc*acc; __syncthreads();
  for (int s = 128; s > 0; s >>= 1) { if (tid < s) { s1[tid]+=s1[tid+s]; s2[tid]+=s2[tid+s]; } __syncthreads(); }
  float m = s1[0]*(1.0f/256.0f), var = s2[0]*(1.0f/256.0f) - m*m;
  float hv = (acc - m)*(1.0f/sqrtf(var + 1e-5f))*lg[tid] + lb[tid];
  hv = lrelu(hv);
  g_h[b*256 + tid] = hv;
  g_cat512[b*512 + tid] = hv;
  g_cat512[b*512 + 256 + tid] = x[128 + tid];
}
__global__ void __launch_bounds__(1024) k_xg0(const float* cwih, const float* cbih, const float* cbhh,
                                              const float* fwih, const float* fbih, const float* fbhh) {
  int bid = blockIdx.x;               // 128 = layer*64+b
  int layer = bid >> 6, b = bid & 63;
  int gp = threadIdx.x, j = gp >> 2, q = gp & 3, g = q*256 + j;
  __shared__ float cat[512];
  if (gp < 512) cat[gp] = g_cat512[b*512 + gp];
  __syncthreads();
  const float* w = layer ? fwih : cwih;
  float acc = layer ? (fbih[g] + fbhh[g]) : (cbih[g] + cbhh[g]);
  for (int k = 0; k < 512; ++k) acc += w[(size_t)g*512 + k]*cat[k];
  g_xg0[(layer*64 + b)*1024 + gp] = acc;
}
__global__ void __launch_bounds__(256) k_osc(const float* w1, const float* b1v, const float* lg,
                                             const float* lb, const float* w2, const float* b2v) {
  __shared__ float hb[256], av[256], s1[256], s2[256];
  int b = blockIdx.x, tid = threadIdx.x;
  hb[tid] = g_h[b*256 + tid];
  __syncthreads();
  float acc = b1v[tid];
  for (int k = 0; k < 256; ++k) acc += w1[tid*256 + k]*hb[k];
  s1[tid] = acc; s2[tid] = acc*acc; __syncthreads();
  for (int s = 128; s > 0; s >>= 1) { if (tid < s) { s1[tid]+=s1[tid+s]; s2[tid]+=s2[tid+s]; } __syncthreads(); }
  float m = s1[0]*(1.0f/256.0f), var = s2[0]*(1.0f/256.0f) - m*m;
  av[tid] = lrelu((acc - m)*(1.0f/sqrtf(var + 1e-5f))*lg[tid] + lb[tid]);
  __syncthreads();
  for (int tt = tid; tt < 1024; tt += 256) {
    float o = b2v[tt];
    for (int i = 0; i < 256; ++i) o += w2[(size_t)tt*256 + i]*av[i];
    g_osc[b*1024 + tt] = tanhf(o);
  }
}
__global__ void __launch_bounds__(256) k_sinmean(const float* sw, const float* sb) {
  int tt = blockIdx.x*256 + threadIdx.x;   // grid 4
  const float F[6] = {0.19f, 0.21f, 0.23f, 0.25f, 0.27f, 0.29f};
  float tl = tt*(1.0f/1023.0f);
  float sc[12];
  for (int j = 0; j < 6; ++j) {
    float p = (6.2831853071795864f * tl) * F[j] * 1024.0f;
    sc[j] = sinf(p); sc[6 + j] = cosf(p);
  }
  float a = 0.0f;
  for (int i = 0; i < 128; ++i) {
    float s = sb[i];
    for (int j = 0; j < 12; ++j) s += sw[i*12 + j]*sc[j];
    a += s;
  }
  g_smean[tt] = a*(1.0f/128.0f);
}

// ---------------- LSTM core (G=2 batches / block, 256 threads) --------------
// thread t owns hidden unit t: gates g'=4t..4t+3 = (i,f,g,o) of unit t; c stays in regs.
__global__ void __launch_bounds__(256) k_lstmA() {
  int bid = blockIdx.x;          // 64: [0,32) coarse, [32,64) f0
  int layer = bid >> 5, pair = bid & 31;
  int b0 = pair*2, b1 = b0 + 1;
  int t = threadIdx.x;
  const f16x2* W = (const f16x2*)g_whhT2 + (size_t)layer*131072u;
  const f16x8* Wl = (const f16x8*)(W + 4*t);
  __shared__ __align__(16) f16 hbuf[2][2][256];
  float accX[4][2];
  {
    f32x4 v0 = *(const f32x4*)(g_xg0 + (layer*64 + b0)*1024 + 4*t);
    f32x4 v1 = *(const f32x4*)(g_xg0 + (layer*64 + b1)*1024 + 4*t);
    for (int q = 0; q < 4; ++q) { accX[q][0] = v0[q]; accX[q][1] = v1[q]; }
  }
  hbuf[0][0][t] = (f16)0.0f; hbuf[0][1][t] = (f16)0.0f;
  float c0 = 0.0f, c1 = 0.0f, sum0 = 0.0f, sum1 = 0.0f;
  __syncthreads();
  f16* outp0; f16* outp1; int ostride;
  if (layer == 0) { outp0 = g_Xpad + (size_t)b0*526336u + 1024 + t; outp1 = g_Xpad + (size_t)b1*526336u + 1024 + t; ostride = 512; }
  else           { outp0 = g_fseqA + (size_t)b0*262144u + t;        outp1 = g_fseqA + (size_t)b1*262144u + t;        ostride = 256; }
  int cur = 0;
  for (int step = 0; step < 1024; ++step) {
    float acc[4][2];
#pragma unroll
    for (int q = 0; q < 4; ++q) { acc[q][0] = accX[q][0]; acc[q][1] = accX[q][1]; }
    const f16* hb0 = &hbuf[cur][0][0];
    const f16* hb1 = &hbuf[cur][1][0];
#pragma unroll
    for (int kb = 0; kb < 8; ++kb) {
      f16x2 hp0[16], hp1[16];
#pragma unroll
      for (int j = 0; j < 4; ++j) {
        expand8(*(const f16x8*)(hb0 + kb*32 + j*8), &hp0[j*4]);
        expand8(*(const f16x8*)(hb1 + kb*32 + j*8), &hp1[j*4]);
      }
      const f16x8* wp = Wl + (size_t)(kb*16)*256u;
#pragma unroll
      for (int li = 0; li < 16; ++li) {
        f16x8 wv = wp[(size_t)li*256u];
        f16x2 w0 = __builtin_shufflevector(wv, wv, 0, 1);
        f16x2 w1 = __builtin_shufflevector(wv, wv, 2, 3);
        f16x2 w2 = __builtin_shufflevector(wv, wv, 4, 5);
        f16x2 w3 = __builtin_shufflevector(wv, wv, 6, 7);
        acc[0][0] = fdot2f(w0, hp0[li], acc[0][0]);
        acc[1][0] = fdot2f(w1, hp0[li], acc[1][0]);
        acc[2][0] = fdot2f(w2, hp0[li], acc[2][0]);
        acc[3][0] = fdot2f(w3, hp0[li], acc[3][0]);
        acc[0][1] = fdot2f(w0, hp1[li], acc[0][1]);
        acc[1][1] = fdot2f(w1, hp1[li], acc[1][1]);
        acc[2][1] = fdot2f(w2, hp1[li], acc[2][1]);
        acc[3][1] = fdot2f(w3, hp1[li], acc[3][1]);
      }
    }
    float h0, h1;
    { float ii = sigm_fast(acc[0][0]), ff = sigm_fast(acc[1][0]);
      float gg = tanh_fast(acc[2][0]), oo = sigm_fast(acc[3][0]);
      c0 = ff*c0 + ii*gg; h0 = oo*tanh_fast(c0); sum0 += h0; }
    { float ii = sigm_fast(acc[0][1]), ff = sigm_fast(acc[1][1]);
      float gg = tanh_fast(acc[2][1]), oo = sigm_fast(acc[3][1]);
      c1 = ff*c1 + ii*gg; h1 = oo*tanh_fast(c1); sum1 += h1; }
    int nxt = cur ^ 1;
    hbuf[nxt][0][t] = (f16)h0;
    hbuf[nxt][1][t] = (f16)h1;
    outp0[(size_t)step*ostride] = (f16)h0;
    outp1[(size_t)step*ostride] = (f16)h1;
    __syncthreads();
    cur = nxt;
  }
  if (layer == 0) {
    g_feats[b0*512 + t] = sum0*(1.0f/1024.0f);
    g_feats[b1*512 + t] = sum1*(1.0f/1024.0f);
  }
}

__global__ void __launch_bounds__(256) k_lstmF(int l) {   // l=0..2 -> fine layers f1..f3
  int pair = blockIdx.x;          // 32
  int b0 = pair*2, b1 = b0 + 1;
  int t = threadIdx.x;
  const f16x2* W = (const f16x2*)g_whhT2 + (size_t)(2 + l)*131072u;
  const f16x8* Wl = (const f16x8*)(W + 4*t);
  __shared__ __align__(16) f16 hbuf[2][2][256];
  const f32x4* xp0 = (const f32x4*)(g_xg32 + (size_t)b0*1048576u + 4*t);
  const f32x4* xp1 = (const f32x4*)(g_xg32 + (size_t)b1*1048576u + 4*t);
  hbuf[0][0][t] = (f16)0.0f; hbuf[0][1][t] = (f16)0.0f;
  float c0 = 0.0f, c1 = 0.0f, sum0 = 0.0f, sum1 = 0.0f;
  __syncthreads();
  f16* outp0; f16* outp1; int ostride;
  if (l == 0)      { outp0 = g_fseqB + (size_t)b0*262144u + t; outp1 = g_fseqB + (size_t)b1*262144u + t; ostride = 256; }
  else if (l == 1) { outp0 = g_fseqA + (size_t)b0*262144u + t; outp1 = g_fseqA + (size_t)b1*262144u + t; ostride = 256; }
  else             { outp0 = g_Xpad + (size_t)b0*526336u + 1024 + 256 + t; outp1 = g_Xpad + (size_t)b1*526336u + 1024 + 256 + t; ostride = 512; }
  int cur = 0;
  for (int step = 0; step < 1024; ++step) {
    f32x4 xv0 = xp0[(size_t)step*256u];
    f32x4 xv1 = xp1[(size_t)step*256u];
    float acc[4][2];
#pragma unroll
    for (int q = 0; q < 4; ++q) { acc[q][0] = 0.0f; acc[q][1] = 0.0f; }
    const f16* hb0 = &hbuf[cur][0][0];
    const f16* hb1 = &hbuf[cur][1][0];
#pragma unroll
    for (int kb = 0; kb < 8; ++kb) {
      f16x2 hp0[16], hp1[16];
#pragma unroll
      for (int j = 0; j < 4; ++j) {
        expand8(*(const f16x8*)(hb0 + kb*32 + j*8), &hp0[j*4]);
        expand8(*(const f16x8*)(hb1 + kb*32 + j*8), &hp1[j*4]);
      }
      const f16x8* wp = Wl + (size_t)(kb*16)*256u;
#pragma unroll
      for (int li = 0; li < 16; ++li) {
        f16x8 wv = wp[(size_t)li*256u];
        f16x2 w0 = __builtin_shufflevector(wv, wv, 0, 1);
        f16x2 w1 = __builtin_shufflevector(wv, wv, 2, 3);
        f16x2 w2 = __builtin_shufflevector(wv, wv, 4, 5);
        f16x2 w3 = __builtin_shufflevector(wv, wv, 6, 7);
        acc[0][0] = fdot2f(w0, hp0[li], acc[0][0]);
        acc[1][0] = fdot2f(w1, hp0[li], acc[1][0]);
        acc[2][0] = fdot2f(w2, hp0[li], acc[2][0]);
        acc[3][0] = fdot2f(w3, hp0[li], acc[3][0]);
        acc[0][1] = fdot2f(w0, hp1[li], acc[0][1]);
        acc[1][1] = fdot2f(w1, hp1[li], acc[1][1]);
        acc[2][1] = fdot2f(w2, hp1[li], acc[2][1]);
        acc[3][1] = fdot2f(w3, hp1[li], acc[3][1]);
      }
    }
    float h0, h1;
    { float ii = sigm_fast(acc[0][0] + xv0[0]), ff = sigm_fast(acc[1][0] + xv0[1]);
      float gg = tanh_fast(acc[2][0] + xv0[2]), oo = sigm_fast(acc[3][0] + xv0[3]);
      c0 = ff*c0 + ii*gg; h0 = oo*tanh_fast(c0); sum0 += h0; }
    { float ii = sigm_fast(acc[0][1] + xv1[0]), ff = sigm_fast(acc[1][1] + xv1[1]);
      float gg = tanh_fast(acc[2][1] + xv1[2]), oo = sigm_fast(acc[3][1] + xv1[3]);
      c1 = ff*c1 + ii*gg; h1 = oo*tanh_fast(c1); sum1 += h1; }
    int nxt = cur ^ 1;
    hbuf[nxt][0][t] = (f16)h0;
    hbuf[nxt][1][t] = (f16)h1;
    outp0[(size_t)step*ostride] = (f16)h0;
    outp1[(size_t)step*ostride] = (f16)h1;
    __syncthreads();
    cur = nxt;
  }
  if (l == 2) {
    g_feats[b0*512 + 256 + t] = sum0*(1.0f/1024.0f);
    g_feats[b1*512 + 256 + t] = sum1*(1.0f/1024.0f);
  }
}

// ---------------- generic fp16 MFMA GEMM (implicit conv / xg projection) ----
// C[m][n] = sum_k A[m][k]*B[n][k];  A rows addressed per (b,t), contiguous K window.
// which: 0 = xg from fseqA, 1 = xg from fseqB, 2 = conv1, 3 = conv2
__global__ void __launch_bounds__(256) k_gemm(int which, int l,
                                              const float* cb, const float* bng, const float* bnb) {
  const f16* A; size_t a_bs; int a_rs, K, N; const f16* Bm; int mode;
  float* outF = nullptr; f16* outH = nullptr; size_t o_bs; int o_rs;
  const float* bias;
  if (which <= 1) {
    A = (which == 0) ? g_fseqA : g_fseqB; a_bs = 262144u; a_rs = 256; K = 256; N = 1024;
    Bm = g_wihB + (size_t)l*262144u; mode = 0; bias = g_biasP + l*1024;
    outF = g_xg32; o_bs = 1048576u; o_rs = 1024;
  } else if (which == 2) {
    A = g_Xpad; a_bs = 526336u; a_rs = 512; K = 2560; N = 256; Bm = g_B1; mode = 1; bias = cb;
    outH = g_c2in + 256; o_bs = 262656u; o_rs = 256;
  } else {
    A = g_c2in; a_bs = 262656u; a_rs = 256; K = 768; N = 128; Bm = g_B2; mode = 1; bias = cb;
    outH = g_c3in; o_bs = 131072u; o_rs = 128;
  }
  int tid = threadIdx.x, wave = tid >> 6, lane = tid & 63;
  int m0 = blockIdx.x*128, n0 = blockIdx.y*64;
  __shared__ __align__(16) f16 Asm[128*72];
  __shared__ __align__(16) f16 Bsm[64*72];
  f32x4 acc[2][4];
#pragma unroll
  for (int i = 0; i < 2; ++i)
#pragma unroll
    for (int j = 0; j < 4; ++j) { f32x4 zz = {0.f,0.f,0.f,0.f}; acc[i][j] = zz; }
  int ar = tid & 127, ac = (tid >> 7)*32;
  int mrow = m0 + ar, abb = mrow >> 10, att = mrow & 1023;
  const f16* aptr = A + (size_t)abb*a_bs + (size_t)att*a_rs + ac;
  int br = tid & 63, bc = (tid >> 6)*16;
  const f16* bptr = Bm + (size_t)(n0 + br)*K + bc;
  int nkb = K >> 6;
  for (int kb = 0; kb < nkb; ++kb) {
    f16x8 av0 = *(const f16x8*)(aptr + 0);
    f16x8 av1 = *(const f16x8*)(aptr + 8);
    f16x8 av2 = *(const f16x8*)(aptr + 16);
    f16x8 av3 = *(const f16x8*)(aptr + 24);
    f16x8 bv0 = *(const f16x8*)(bptr + 0);
    f16x8 bv1 = *(const f16x8*)(bptr + 8);
    aptr += 64; bptr += 64;
    __syncthreads();
    *(f16x8*)(&Asm[ar*72 + ac + 0])  = av0;
    *(f16x8*)(&Asm[ar*72 + ac + 8])  = av1;
    *(f16x8*)(&Asm[ar*72 + ac + 16]) = av2;
    *(f16x8*)(&Asm[ar*72 + ac + 24]) = av3;
    *(f16x8*)(&Bsm[br*72 + bc + 0])  = bv0;
    *(f16x8*)(&Bsm[br*72 + bc + 8])  = bv1;
    __syncthreads();
#pragma unroll
    for (int ks = 0; ks < 2; ++ks) {
      int ko = ks*32 + (lane >> 4)*8;
      f16x8 a0 = *(const f16x8*)(&Asm[(wave*32 + (lane & 15))*72 + ko]);
      f16x8 a1 = *(const f16x8*)(&Asm[(wave*32 + 16 + (lane & 15))*72 + ko]);
#pragma unroll
      for (int nt = 0; nt < 4; ++nt) {
        f16x8 bf = *(const f16x8*)(&Bsm[(nt*16 + (lane & 15))*72 + ko]);
        acc[0][nt] = __builtin_amdgcn_mfma_f32_16x16x32_f16(a0, bf, acc[0][nt], 0, 0, 0);
        acc[1][nt] = __builtin_amdgcn_mfma_f32_16x16x32_f16(a1, bf, acc[1][nt], 0, 0, 0);
      }
    }
  }
  const float bnc = 0.99999500003749969f;  // 1/sqrt(1+1e-5)
#pragma unroll
  for (int mt = 0; mt < 2; ++mt)
#pragma unroll
    for (int nt = 0; nt < 4; ++nt)
#pragma unroll
      for (int r = 0; r < 4; ++r) {
        int m_loc = wave*32 + mt*16 + (lane >> 4)*4 + r;
        int n = n0 + nt*16 + (lane & 15);
        int mg = m0 + m_loc, ob = mg >> 10, ot = mg & 1023;
        float v = acc[mt][nt][r];
        if (mode == 0) {
          v += bias[n];
          outF[(size_t)ob*o_bs + (size_t)ot*o_rs + n] = v;
        } else {
          v = (v + bias[n])*(bng[n]*bnc) + bnb[n];
          v = lrelu(v);
          outH[(size_t)ob*o_bs + (size_t)ot*o_rs + n] = (f16)v;
        }
      }
}

// ---------------- cp head / cardiac params ----------------------------------
__global__ void __launch_bounds__(128) k_cp(const float* w1, const float* b1v, const float* lg,
                                            const float* lb, const float* w2, const float* b2v) {
  __shared__ float ft[512], av[128], s1[128], s2[128];
  int b = blockIdx.x, tid = threadIdx.x;
  for (int i = tid; i < 512; i += 128) ft[i] = g_feats[b*512 + i];
  __syncthreads();
  float acc = b1v[tid];
  for (int k = 0; k < 512; ++k) acc += w1[tid*512 + k]*ft[k];
  s1[tid] = acc; s2[tid] = acc*acc; __syncthreads();
  for (int s = 64; s > 0; s >>= 1) { if (tid < s) { s1[tid]+=s1[tid+s]; s2[tid]+=s2[tid+s]; } __syncthreads(); }
  float m = s1[0]*(1.0f/128.0f), var = s2[0]*(1.0f/128.0f) - m*m;
  av[tid] = lrelu((acc - m)*(1.0f/sqrtf(var + 1e-5f))*lg[tid] + lb[tid]);
  __syncthreads();
  if (tid < 4) {
    float s = b2v[tid];
    for (int i = 0; i < 128; ++i) s += w2[tid*128 + i]*av[i];
    g_cpar[b*4 + tid] = 1.0f/(1.0f + expf(-s));
  }
}

// ---------------- conv3 + enhanced ------------------------------------------
__global__ void __launch_bounds__(256) k_enh(const float* w3, const float* b3) {
  int idx = blockIdx.x*256 + threadIdx.x;
  int b = idx >> 10, t = idx & 1023;
  const f16* xc = g_c3in + (size_t)idx*128u;
  bool hm = (t > 0), hp = (t < 1023);
  float pre = b3[0];
  for (int c = 0; c < 128; ++c) {
    float xm = hm ? (float)xc[c - 128] : 0.0f;
    float x0 = (float)xc[c];
    float xp = hp ? (float)xc[c + 128] : 0.0f;
    pre += xm*w3[c*3] + x0*w3[c*3 + 1] + xp*w3[c*3 + 2];
  }
  float base = tanhf(pre);
  float cp0 = g_cpar[b*4 + 0], cp1 = g_cpar[b*4 + 1], cp2 = g_cpar[b*4 + 2], cp3 = g_cpar[b*4 + 3];
  float freq  = 0.19f + 0.1f*cp0;
  float amp   = 1.0f + 2.0f*cp1;
  float phase = 6.2831853071795864f*cp2;
  float basel = -0.5f + cp3;
  float tl = t*(1.0f/1023.0f);
  float arg = ((6.2831853071795864f*freq)*1024.0f)*tl + phase;
  float card = amp*sinf(arg) + basel;
  g_enh[idx] = 0.1f*base + 0.1f*g_osc[idx] + 0.7f*card + 0.1f*g_smean[t];
}

__global__ void __launch_bounds__(256) k_out(const int* labels, const float* sw,
                                             const float* aw, const float* ab, float* out) {
  int idx = blockIdx.x*256 + threadIdx.x;
  int b = idx >> 10, t = idx & 1023;
  int lab = labels[b];
  float e = g_enh[idx], r;
  if (lab == 1) r = e;
  else if (lab == 2) r = sw[0]*e;
  else if (lab == 3) {
    float em = (t > 0)    ? g_enh[idx - 1] : 0.0f;
    float ep = (t < 1023) ? g_enh[idx + 1] : 0.0f;
    r = aw[0]*em + aw[1]*e + aw[2]*ep + ab[0];
  } else r = 0.0f;
  out[idx] = r;
}

// ---------------- launch -----------------------------------------------------
extern "C" void kernel_launch(void* const* d_in, const int* in_sizes, int n_in,
                              void* d_out, int out_size, void* d_ws, size_t ws_size,
                              hipStream_t stream) {
  const float* z       = (const float*)d_in[0];
  const int*   labels  = (const int*)  d_in[1];
  const float* emb     = (const float*)d_in[2];
  const float* np_w    = (const float*)d_in[3];
  const float* np_b    = (const float*)d_in[4];
  const float* np_ln_g = (const float*)d_in[5];
  const float* np_ln_b = (const float*)d_in[6];
  const float* c_wih   = (const float*)d_in[7];
  const float* c_whh   = (const float*)d_in[8];
  const float* c_bih   = (const float*)d_in[9];
  const float* c_bhh   = (const float*)d_in[10];
  const float* f0_wih  = (const float*)d_in[11];
  const float* f0_whh  = (const float*)d_in[12];
  const float* f0_bih  = (const float*)d_in[13];
  const float* f0_bhh  = (const float*)d_in[14];
  const float* f_wih   = (const float*)d_in[15];
  const float* f_whh   = (const float*)d_in[16];
  const float* f_bih   = (const float*)d_in[17];
  const float* f_bhh   = (const float*)d_in[18];
  const float* osc_w1  = (const float*)d_in[19];
  const float* osc_b1  = (const float*)d_in[20];
  const float* osc_ln_g= (const float*)d_in[21];
  const float* osc_ln_b= (const float*)d_in[22];
  const float* osc_w2  = (const float*)d_in[23];
  const float* osc_b2  = (const float*)d_in[24];
  const float* cp_w1   = (const float*)d_in[25];
  const float* cp_b1   = (const float*)d_in[26];
  const float* cp_ln_g = (const float*)d_in[27];
  const float* cp_ln_b = (const float*)d_in[28];
  const float* cp_w2   = (const float*)d_in[29];
  const float* cp_b2   = (const float*)d_in[30];
  const float* sin_w   = (const float*)d_in[31];
  const float* sin_b   = (const float*)d_in[32];
  const float* conv1_w = (const float*)d_in[33];
  const float* conv1_b = (const float*)d_in[34];
  const float* bn1_g   = (const float*)d_in[35];
  const float* bn1_b   = (const float*)d_in[36];
  const float* conv2_w = (const float*)d_in[37];
  const float* conv2_b = (const float*)d_in[38];
  const float* bn2_g   = (const float*)d_in[39];
  const float* bn2_b   = (const float*)d_in[40];
  const float* conv3_w = (const float*)d_in[41];
  const float* conv3_b = (const float*)d_in[42];
  const float* stress_w= (const float*)d_in[43];
  const float* amuse_w = (const float*)d_in[44];
  const float* amuse_b = (const float*)d_in[45];
  float* out = (float*)d_out;

  k_prep_whh<<<5120, 256, 0, stream>>>(c_whh, f0_whh, f_whh);
  k_prep_wih<<<3072, 256, 0, stream>>>(f_wih, f_bih, f_bhh);
  k_prep_c1 <<<2560, 256, 0, stream>>>(conv1_w);
  k_prep_c2 <<< 384, 256, 0, stream>>>(conv2_w);
  k_zero    <<< 640, 256, 0, stream>>>();
  k_setup1  <<<  64, 256, 0, stream>>>(z, labels, emb, np_w, np_b, np_ln_g, np_ln_b);
  k_xg0     <<< 128,1024, 0, stream>>>(c_wih, c_bih, c_bhh, f0_wih, f0_bih, f0_bhh);
  k_osc     <<<  64, 256, 0, stream>>>(osc_w1, osc_b1, osc_ln_g, osc_ln_b, osc_w2, osc_b2);
  k_sinmean <<<   4, 256, 0, stream>>>(sin_w, sin_b);

  k_lstmA   <<<  64, 256, 0, stream>>>();                       // coarse + f0 concurrently
  for (int l = 0; l < 3; ++l) {                                 // f1, f2, f3
    int which = (l == 1) ? 1 : 0;                               // input seq ping-pong
    k_gemm  <<<dim3(512,16), 256, 0, stream>>>(which, l, nullptr, nullptr, nullptr);
    k_lstmF <<<  32, 256, 0, stream>>>(l);
  }
  k_cp      <<<  64, 128, 0, stream>>>(cp_w1, cp_b1, cp_ln_g, cp_ln_b, cp_w2, cp_b2);
  k_gemm    <<<dim3(512, 4), 256, 0, stream>>>(2, 0, conv1_b, bn1_g, bn1_b);   // conv1
  k_gemm    <<<dim3(512, 2), 256, 0, stream>>>(3, 0, conv2_b, bn2_g, bn2_b);   // conv2
  k_enh     <<< 256, 256, 0, stream>>>(conv3_w, conv3_b);
  k_out     <<< 256, 256, 0, stream>>>(labels, stress_w, amuse_w, amuse_b, out);
}

// Round 2
// 65133.032 us; speedup vs baseline: 1.0581x; 1.0581x over previous
//
#include <hip/hip_runtime.h>

typedef _Float16 f16;
typedef _Float16 f16x2 __attribute__((ext_vector_type(2)));
typedef _Float16 f16x8 __attribute__((ext_vector_type(8)));
typedef float    f32x4 __attribute__((ext_vector_type(4)));

// ---------------- static device scratch (avoids ws_size assumptions) --------
__device__ f16   g_Xpad [64u*1028u*512u];   // conv1 input (B,T+4,512): ch0-255 coarse, 256-511 fine(final)
__device__ f16   g_fseqA[64u*1024u*256u];   // fine sequence ping
__device__ f16   g_fseqB[64u*1024u*256u];   // fine sequence pong
__device__ float g_xg32 [64u*1024u*1024u];  // per-f-layer input projection, permuted gate order, fp32
__device__ f16   g_c2in [64u*1026u*256u];   // conv2 input (B,T+2,256), padded
__device__ f16   g_c3in [64u*1024u*128u];   // conv3 input (B,T,128)
__device__ f16   g_whhT2[5u*262144u];       // [L][k2][g'][2] fp16, permuted gate rows
__device__ f16   g_wihB [3u*262144u];       // [l][g'][k] fp16, permuted gate rows
__device__ float g_biasP[3*1024];           // permuted bih+bhh for f1..f3
__device__ f16   g_B1   [256u*2560u];       // conv1 weight as GEMM B [oc][r*512+ic]
__device__ f16   g_B2   [128u*768u];        // conv2 weight as GEMM B [oc][r*256+ic]
__device__ float g_xg0  [2*64*1024];        // static xg for coarse/f0, permuted
__device__ float g_cat512[64*512];          // [h, le]
__device__ float g_h    [64*256];
__device__ float g_feats[64*512];           // [coarse.mean, fine.mean]
__device__ float g_osc  [64*1024];
__device__ float g_smean[1024];
__device__ float g_cpar [64*4];             // raw cp sigmoid outputs
__device__ float g_enh  [64*1024];

// ---------------- helpers ---------------------------------------------------
__device__ inline float fdot2f(f16x2 a, f16x2 b, float c) {
#if __has_builtin(__builtin_amdgcn_fdot2)
  return __builtin_amdgcn_fdot2(a, b, c, false);
#else
  return c + (float)a[0]*(float)b[0] + (float)a[1]*(float)b[1];
#endif
}
__device__ inline float sigm_fast(float x) { return 1.0f / (1.0f + __expf(-x)); }
__device__ inline float tanh_fast(float x) { float e = __expf(2.0f*x); return 1.0f - 2.0f/(e + 1.0f); }
__device__ inline float lrelu(float x) { return x < 0.0f ? 0.2f*x : x; }
__device__ inline void expand8(f16x8 v, f16x2* dst) {
  dst[0] = __builtin_shufflevector(v, v, 0, 1);
  dst[1] = __builtin_shufflevector(v, v, 2, 3);
  dst[2] = __builtin_shufflevector(v, v, 4, 5);
  dst[3] = __builtin_shufflevector(v, v, 6, 7);
}

// ---------------- weight prep ----------------------------------------------
// permuted gate order: g' = j*4+q  <->  g = q*256+j   (q: 0=i,1=f,2=g,3=o)
__global__ void __launch_bounds__(256) k_prep_whh(const float* cw, const float* f0w, const float* fw) {
  int bid = blockIdx.x;               // 5*1024
  int L = bid >> 10, gp = bid & 1023, k = threadIdx.x;
  const float* src = (L == 0) ? cw : (L == 1) ? f0w : (fw + (size_t)(L-2)*262144u);
  int j = gp >> 2, q = gp & 3, g = q*256 + j;
  float v = src[(size_t)g*256 + k];
  g_whhT2[(size_t)L*262144u + (size_t)(k>>1)*2048u + (size_t)gp*2u + (k&1)] = (f16)v;
}
__global__ void __launch_bounds__(256) k_prep_wih(const float* fwih, const float* fbih, const float* fbhh) {
  int bid = blockIdx.x;               // 3*1024
  int L = bid >> 10, gp = bid & 1023, k = threadIdx.x;
  int j = gp >> 2, q = gp & 3, g = q*256 + j;
  g_wihB[(size_t)L*262144u + (size_t)gp*256u + k] = (f16)fwih[(size_t)L*262144u + (size_t)g*256u + k];
  if (k == 0) g_biasP[L*1024 + gp] = fbih[L*1024 + g] + fbhh[L*1024 + g];
}
__global__ void __launch_bounds__(256) k_prep_c1(const float* w) {
  int idx = blockIdx.x*256 + threadIdx.x;        // 655360
  int oc = idx / 2560, rem = idx % 2560, r = rem / 512, ic = rem % 512;
  g_B1[idx] = (f16)w[(size_t)oc*2560 + (size_t)ic*5 + r];
}
__global__ void __launch_bounds__(256) k_prep_c2(const float* w) {
  int idx = blockIdx.x*256 + threadIdx.x;        // 98304
  int oc = idx / 768, rem = idx % 768, r = rem / 256, ic = rem % 256;
  g_B2[idx] = (f16)w[(size_t)oc*768 + (size_t)ic*3 + r];
}
__global__ void __launch_bounds__(256) k_zero() {
  int idx = blockIdx.x*256 + threadIdx.x;        // 163840
  if (idx < 131072) {   // Xpad pad rows 0,1,1026,1027
    int b = idx >> 11, rem = idx & 2047, rr = rem >> 9, c = rem & 511;
    int row = (rr < 2) ? rr : 1024 + rr;
    g_Xpad[(size_t)b*526336u + (size_t)row*512u + c] = (f16)0.0f;
  } else {              // c2in pad rows 0, 1025
    int i2 = idx - 131072;
    int b = i2 >> 9, rem = i2 & 511, rr = rem >> 8, c = rem & 255;
    int row = rr ? 1025 : 0;
    g_c2in[(size_t)b*262656u + (size_t)row*256u + c] = (f16)0.0f;
  }
}

// ---------------- small front-end ops ---------------------------------------
__global__ void __launch_bounds__(256) k_setup1(const float* z, const int* labels, const float* emb,
                                                const float* npw, const float* npb,
                                                const float* lg, const float* lb) {
  __shared__ float x[384];
  __shared__ float s1[256], s2[256];
  int b = blockIdx.x, tid = threadIdx.x;
  int lab = labels[b];
  for (int i = tid; i < 384; i += 256)
    x[i] = (i < 128) ? z[b*128 + i] : emb[lab*256 + (i - 128)];
  __syncthreads();
  float acc = npb[tid];
  for (int k = 0; k < 384; ++k) acc += npw[tid*384 + k]*x[k];
  s1[tid] = acc; s2[tid] = acc*acc; __syncthreads();
  for (int s = 128; s > 0; s >>= 1) { if (tid < s) { s1[tid]+=s1[tid+s]; s2[tid]+=s2[tid+s]; } __syncthreads(); }
  float m = s1[0]*(1.0f/256.0f), var = s2[0]*(1.0f/256.0f) - m*m;
  float hv = (acc - m)*(1.0f/sqrtf(var + 1e-5f))*lg[tid] + lb[tid];
  hv = lrelu(hv);
  g_h[b*256 + tid] = hv;
  g_cat512[b*512 + tid] = hv;
  g_cat512[b*512 + 256 + tid] = x[128 + tid];
}
__global__ void __launch_bounds__(1024) k_xg0(const float* cwih, const float* cbih, const float* cbhh,
                                              const float* fwih, const float* fbih, const float* fbhh) {
  int bid = blockIdx.x;               // 128 = layer*64+b
  int layer = bid >> 6, b = bid & 63;
  int gp = threadIdx.x, j = gp >> 2, q = gp & 3, g = q*256 + j;
  __shared__ float cat[512];
  if (gp < 512) cat[gp] = g_cat512[b*512 + gp];
  __syncthreads();
  const float* w = layer ? fwih : cwih;
  float acc = layer ? (fbih[g] + fbhh[g]) : (cbih[g] + cbhh[g]);
  for (int k = 0; k < 512; ++k) acc += w[(size_t)g*512 + k]*cat[k];
  g_xg0[(layer*64 + b)*1024 + gp] = acc;
}
__global__ void __launch_bounds__(256) k_osc(const float* w1, const float* b1v, const float* lg,
                                             const float* lb, const float* w2, const float* b2v) {
  __shared__ float hb[256], av[256], s1[256], s2[256];
  int b = blockIdx.x, tid = threadIdx.x;
  hb[tid] = g_h[b*256 + tid];
  __syncthreads();
  float acc = b1v[tid];
  for (int k = 0; k < 256; ++k) acc += w1[tid*256 + k]*hb[k];
  s1[tid] = acc; s2[tid] = acc*acc; __syncthreads();
  for (int s = 128; s > 0; s >>= 1) { if (tid < s) { s1[tid]+=s1[tid+s]; s2[tid]+=s2[tid+s]; } __syncthreads(); }
  float m = s1[0]*(1.0f/256.0f), var = s2[0]*(1.0f/256.0f) - m*m;
  av[tid] = lrelu((acc - m)*(1.0f/sqrtf(var + 1e-5f))*lg[tid] + lb[tid]);
  __syncthreads();
  for (int tt = tid; tt < 1024; tt += 256) {
    float o = b2v[tt];
    for (int i = 0; i < 256; ++i) o += w2[(size_t)tt*256 + i]*av[i];
    g_osc[b*1024 + tt] = tanhf(o);
  }
}
__global__ void __launch_bounds__(256) k_sinmean(const float* sw, const float* sb) {
  int tt = blockIdx.x*256 + threadIdx.x;   // grid 4
  const float F[6] = {0.19f, 0.21f, 0.23f, 0.25f, 0.27f, 0.29f};
  float tl = tt*(1.0f/1023.0f);
  float sc[12];
  for (int j = 0; j < 6; ++j) {
    float p = (6.2831853071795864f * tl) * F[j] * 1024.0f;
    sc[j] = sinf(p); sc[6 + j] = cosf(p);
  }
  float a = 0.0f;
  for (int i = 0; i < 128; ++i) {
    float s = sb[i];
    for (int j = 0; j < 12; ++j) s += sw[i*12 + j]*sc[j];
    a += s;
  }
  g_smean[tt] = a*(1.0f/128.0f);
}

// ---------------- LSTM core (G=2 batches / block, 256 threads) --------------
// thread t owns hidden unit t: gates g'=4t..4t+3 = (i,f,g,o) of unit t; c stays in regs.
// Weights double-buffered in registers (wbuf[2][16] f16x8 = 128 VGPRs in flight):
// kb+1's 16 loads are issued before computing kb; kb==7 slot re-prefetches kb=0
// (weights are step-invariant). __launch_bounds__(256,1) lifts the VGPR budget so
// the compiler doesn't serialize loads (R0: 46us/step = 128 serialized L2 trips).
__global__ void __launch_bounds__(256, 1) k_lstmA() {
  int bid = blockIdx.x;          // 64: [0,32) coarse, [32,64) f0
  int layer = bid >> 5, pair = bid & 31;
  int b0 = pair*2, b1 = b0 + 1;
  int t = threadIdx.x;
  const f16x2* W = (const f16x2*)g_whhT2 + (size_t)layer*131072u;
  const f16x8* Wl = (const f16x8*)(W + 4*t);
  __shared__ __align__(16) f16 hbuf[2][2][256];
  float accX[4][2];
  {
    f32x4 v0 = *(const f32x4*)(g_xg0 + (layer*64 + b0)*1024 + 4*t);
    f32x4 v1 = *(const f32x4*)(g_xg0 + (layer*64 + b1)*1024 + 4*t);
    for (int q = 0; q < 4; ++q) { accX[q][0] = v0[q]; accX[q][1] = v1[q]; }
  }
  hbuf[0][0][t] = (f16)0.0f; hbuf[0][1][t] = (f16)0.0f;
  float c0 = 0.0f, c1 = 0.0f, sum0 = 0.0f, sum1 = 0.0f;
  f16x8 wbuf[2][16];
#pragma unroll
  for (int li = 0; li < 16; ++li) wbuf[0][li] = Wl[(size_t)li*256u];
  __syncthreads();
  f16* outp0; f16* outp1; int ostride;
  if (layer == 0) { outp0 = g_Xpad + (size_t)b0*526336u + 1024 + t; outp1 = g_Xpad + (size_t)b1*526336u + 1024 + t; ostride = 512; }
  else           { outp0 = g_fseqA + (size_t)b0*262144u + t;        outp1 = g_fseqA + (size_t)b1*262144u + t;        ostride = 256; }
  int cur = 0;
  for (int step = 0; step < 1024; ++step) {
    float acc[4][2];
#pragma unroll
    for (int q = 0; q < 4; ++q) { acc[q][0] = accX[q][0]; acc[q][1] = accX[q][1]; }
    const f16* hb0 = &hbuf[cur][0][0];
    const f16* hb1 = &hbuf[cur][1][0];
#pragma unroll
    for (int kb = 0; kb < 8; ++kb) {
      int nb = (kb + 1) & 1, cb2 = kb & 1;
      int nkb = (kb + 1) & 7;          // kb==7 -> re-prefetch kb=0 for next step
      const f16x8* wp = Wl + (size_t)(nkb*16)*256u;
#pragma unroll
      for (int li = 0; li < 16; ++li) wbuf[nb][li] = wp[(size_t)li*256u];
      f16x2 hp0[16], hp1[16];
#pragma unroll
      for (int j = 0; j < 4; ++j) {
        expand8(*(const f16x8*)(hb0 + kb*32 + j*8), &hp0[j*4]);
        expand8(*(const f16x8*)(hb1 + kb*32 + j*8), &hp1[j*4]);
      }
#pragma unroll
      for (int li = 0; li < 16; ++li) {
        f16x8 wv = wbuf[cb2][li];
        f16x2 w0 = __builtin_shufflevector(wv, wv, 0, 1);
        f16x2 w1 = __builtin_shufflevector(wv, wv, 2, 3);
        f16x2 w2 = __builtin_shufflevector(wv, wv, 4, 5);
        f16x2 w3 = __builtin_shufflevector(wv, wv, 6, 7);
        acc[0][0] = fdot2f(w0, hp0[li], acc[0][0]);
        acc[1][0] = fdot2f(w1, hp0[li], acc[1][0]);
        acc[2][0] = fdot2f(w2, hp0[li], acc[2][0]);
        acc[3][0] = fdot2f(w3, hp0[li], acc[3][0]);
        acc[0][1] = fdot2f(w0, hp1[li], acc[0][1]);
        acc[1][1] = fdot2f(w1, hp1[li], acc[1][1]);
        acc[2][1] = fdot2f(w2, hp1[li], acc[2][1]);
        acc[3][1] = fdot2f(w3, hp1[li], acc[3][1]);
      }
    }
    float h0, h1;
    { float ii = sigm_fast(acc[0][0]), ff = sigm_fast(acc[1][0]);
      float gg = tanh_fast(acc[2][0]), oo = sigm_fast(acc[3][0]);
      c0 = ff*c0 + ii*gg; h0 = oo*tanh_fast(c0); sum0 += h0; }
    { float ii = sigm_fast(acc[0][1]), ff = sigm_fast(acc[1][1]);
      float gg = tanh_fast(acc[2][1]), oo = sigm_fast(acc[3][1]);
      c1 = ff*c1 + ii*gg; h1 = oo*tanh_fast(c1); sum1 += h1; }
    int nxt = cur ^ 1;
    hbuf[nxt][0][t] = (f16)h0;
    hbuf[nxt][1][t] = (f16)h1;
    outp0[(size_t)step*ostride] = (f16)h0;
    outp1[(size_t)step*ostride] = (f16)h1;
    __syncthreads();
    cur = nxt;
  }
  if (layer == 0) {
    g_feats[b0*512 + t] = sum0*(1.0f/1024.0f);
    g_feats[b1*512 + t] = sum1*(1.0f/1024.0f);
  }
}

__global__ void __launch_bounds__(256, 1) k_lstmF(int l) {   // l=0..2 -> fine layers f1..f3
  int pair = blockIdx.x;          // 32
  int b0 = pair*2, b1 = b0 + 1;
  int t = threadIdx.x;
  const f16x2* W = (const f16x2*)g_whhT2 + (size_t)(2 + l)*131072u;
  const f16x8* Wl = (const f16x8*)(W + 4*t);
  __shared__ __align__(16) f16 hbuf[2][2][256];
  const f32x4* xp0 = (const f32x4*)(g_xg32 + (size_t)b0*1048576u + 4*t);
  const f32x4* xp1 = (const f32x4*)(g_xg32 + (size_t)b1*1048576u + 4*t);
  hbuf[0][0][t] = (f16)0.0f; hbuf[0][1][t] = (f16)0.0f;
  float c0 = 0.0f, c1 = 0.0f, sum0 = 0.0f, sum1 = 0.0f;
  f16x8 wbuf[2][16];
#pragma unroll
  for (int li = 0; li < 16; ++li) wbuf[0][li] = Wl[(size_t)li*256u];
  __syncthreads();
  f16* outp0; f16* outp1; int ostride;
  if (l == 0)      { outp0 = g_fseqB + (size_t)b0*262144u + t; outp1 = g_fseqB + (size_t)b1*262144u + t; ostride = 256; }
  else if (l == 1) { outp0 = g_fseqA + (size_t)b0*262144u + t; outp1 = g_fseqA + (size_t)b1*262144u + t; ostride = 256; }
  else             { outp0 = g_Xpad + (size_t)b0*526336u + 1024 + 256 + t; outp1 = g_Xpad + (size_t)b1*526336u + 1024 + 256 + t; ostride = 512; }
  int cur = 0;
  for (int step = 0; step < 1024; ++step) {
    f32x4 xv0 = xp0[(size_t)step*256u];
    f32x4 xv1 = xp1[(size_t)step*256u];
    float acc[4][2];
#pragma unroll
    for (int q = 0; q < 4; ++q) { acc[q][0] = 0.0f; acc[q][1] = 0.0f; }
    const f16* hb0 = &hbuf[cur][0][0];
    const f16* hb1 = &hbuf[cur][1][0];
#pragma unroll
    for (int kb = 0; kb < 8; ++kb) {
      int nb = (kb + 1) & 1, cb2 = kb & 1;
      int nkb = (kb + 1) & 7;          // kb==7 -> re-prefetch kb=0 for next step
      const f16x8* wp = Wl + (size_t)(nkb*16)*256u;
#pragma unroll
      for (int li = 0; li < 16; ++li) wbuf[nb][li] = wp[(size_t)li*256u];
      f16x2 hp0[16], hp1[16];
#pragma unroll
      for (int j = 0; j < 4; ++j) {
        expand8(*(const f16x8*)(hb0 + kb*32 + j*8), &hp0[j*4]);
        expand8(*(const f16x8*)(hb1 + kb*32 + j*8), &hp1[j*4]);
      }
#pragma unroll
      for (int li = 0; li < 16; ++li) {
        f16x8 wv = wbuf[cb2][li];
        f16x2 w0 = __builtin_shufflevector(wv, wv, 0, 1);
        f16x2 w1 = __builtin_shufflevector(wv, wv, 2, 3);
        f16x2 w2 = __builtin_shufflevector(wv, wv, 4, 5);
        f16x2 w3 = __builtin_shufflevector(wv, wv, 6, 7);
        acc[0][0] = fdot2f(w0, hp0[li], acc[0][0]);
        acc[1][0] = fdot2f(w1, hp0[li], acc[1][0]);
        acc[2][0] = fdot2f(w2, hp0[li], acc[2][0]);
        acc[3][0] = fdot2f(w3, hp0[li], acc[3][0]);
        acc[0][1] = fdot2f(w0, hp1[li], acc[0][1]);
        acc[1][1] = fdot2f(w1, hp1[li], acc[1][1]);
        acc[2][1] = fdot2f(w2, hp1[li], acc[2][1]);
        acc[3][1] = fdot2f(w3, hp1[li], acc[3][1]);
      }
    }
    float h0, h1;
    { float ii = sigm_fast(acc[0][0] + xv0[0]), ff = sigm_fast(acc[1][0] + xv0[1]);
      float gg = tanh_fast(acc[2][0] + xv0[2]), oo = sigm_fast(acc[3][0] + xv0[3]);
      c0 = ff*c0 + ii*gg; h0 = oo*tanh_fast(c0); sum0 += h0; }
    { float ii = sigm_fast(acc[0][1] + xv1[0]), ff = sigm_fast(acc[1][1] + xv1[1]);
      float gg = tanh_fast(acc[2][1] + xv1[2]), oo = sigm_fast(acc[3][1] + xv1[3]);
      c1 = ff*c1 + ii*gg; h1 = oo*tanh_fast(c1); sum1 += h1; }
    int nxt = cur ^ 1;
    hbuf[nxt][0][t] = (f16)h0;
    hbuf[nxt][1][t] = (f16)h1;
    outp0[(size_t)step*ostride] = (f16)h0;
    outp1[(size_t)step*ostride] = (f16)h1;
    __syncthreads();
    cur = nxt;
  }
  if (l == 2) {
    g_feats[b0*512 + 256 + t] = sum0*(1.0f/1024.0f);
    g_feats[b1*512 + 256 + t] = sum1*(1.0f/1024.0f);
  }
}

// ---------------- generic fp16 MFMA GEMM (implicit conv / xg projection) ----
// C[m][n] = sum_k A[m][k]*B[n][k];  A rows addressed per (b,t), contiguous K window.
// which: 0 = xg from fseqA, 1 = xg from fseqB, 2 = conv1, 3 = conv2
__global__ void __launch_bounds__(256) k_gemm(int which, int l,
                                              const float* cb, const float* bng, const float* bnb) {
  const f16* A; size_t a_bs; int a_rs, K, N; const f16* Bm; int mode;
  float* outF = nullptr; f16* outH = nullptr; size_t o_bs; int o_rs;
  const float* bias;
  if (which <= 1) {
    A = (which == 0) ? g_fseqA : g_fseqB; a_bs = 262144u; a_rs = 256; K = 256; N = 1024;
    Bm = g_wihB + (size_t)l*262144u; mode = 0; bias = g_biasP + l*1024;
    outF = g_xg32; o_bs = 1048576u; o_rs = 1024;
  } else if (which == 2) {
    A = g_Xpad; a_bs = 526336u; a_rs = 512; K = 2560; N = 256; Bm = g_B1; mode = 1; bias = cb;
    outH = g_c2in + 256; o_bs = 262656u; o_rs = 256;
  } else {
    A = g_c2in; a_bs = 262656u; a_rs = 256; K = 768; N = 128; Bm = g_B2; mode = 1; bias = cb;
    outH = g_c3in; o_bs = 131072u; o_rs = 128;
  }
  int tid = threadIdx.x, wave = tid >> 6, lane = tid & 63;
  int m0 = blockIdx.x*128, n0 = blockIdx.y*64;
  __shared__ __align__(16) f16 Asm[128*72];
  __shared__ __align__(16) f16 Bsm[64*72];
  f32x4 acc[2][4];
#pragma unroll
  for (int i = 0; i < 2; ++i)
#pragma unroll
    for (int j = 0; j < 4; ++j) { f32x4 zz = {0.f,0.f,0.f,0.f}; acc[i][j] = zz; }
  int ar = tid & 127, ac = (tid >> 7)*32;
  int mrow = m0 + ar, abb = mrow >> 10, att = mrow & 1023;
  const f16* aptr = A + (size_t)abb*a_bs + (size_t)att*a_rs + ac;
  int br = tid & 63, bc = (tid >> 6)*16;
  const f16* bptr = Bm + (size_t)(n0 + br)*K + bc;
  int nkb = K >> 6;
  for (int kb = 0; kb < nkb; ++kb) {
    f16x8 av0 = *(const f16x8*)(aptr + 0);
    f16x8 av1 = *(const f16x8*)(aptr + 8);
    f16x8 av2 = *(const f16x8*)(aptr + 16);
    f16x8 av3 = *(const f16x8*)(aptr + 24);
    f16x8 bv0 = *(const f16x8*)(bptr + 0);
    f16x8 bv1 = *(const f16x8*)(bptr + 8);
    aptr += 64; bptr += 64;
    __syncthreads();
    *(f16x8*)(&Asm[ar*72 + ac + 0])  = av0;
    *(f16x8*)(&Asm[ar*72 + ac + 8])  = av1;
    *(f16x8*)(&Asm[ar*72 + ac + 16]) = av2;
    *(f16x8*)(&Asm[ar*72 + ac + 24]) = av3;
    *(f16x8*)(&Bsm[br*72 + bc + 0])  = bv0;
    *(f16x8*)(&Bsm[br*72 + bc + 8])  = bv1;
    __syncthreads();
#pragma unroll
    for (int ks = 0; ks < 2; ++ks) {
      int ko = ks*32 + (lane >> 4)*8;
      f16x8 a0 = *(const f16x8*)(&Asm[(wave*32 + (lane & 15))*72 + ko]);
      f16x8 a1 = *(const f16x8*)(&Asm[(wave*32 + 16 + (lane & 15))*72 + ko]);
#pragma unroll
      for (int nt = 0; nt < 4; ++nt) {
        f16x8 bf = *(const f16x8*)(&Bsm[(nt*16 + (lane & 15))*72 + ko]);
        acc[0][nt] = __builtin_amdgcn_mfma_f32_16x16x32_f16(a0, bf, acc[0][nt], 0, 0, 0);
        acc[1][nt] = __builtin_amdgcn_mfma_f32_16x16x32_f16(a1, bf, acc[1][nt], 0, 0, 0);
      }
    }
  }
  const float bnc = 0.99999500003749969f;  // 1/sqrt(1+1e-5)
#pragma unroll
  for (int mt = 0; mt < 2; ++mt)
#pragma unroll
    for (int nt = 0; nt < 4; ++nt)
#pragma unroll
      for (int r = 0; r < 4; ++r) {
        int m_loc = wave*32 + mt*16 + (lane >> 4)*4 + r;
        int n = n0 + nt*16 + (lane & 15);
        int mg = m0 + m_loc, ob = mg >> 10, ot = mg & 1023;
        float v = acc[mt][nt][r];
        if (mode == 0) {
          v += bias[n];
          outF[(size_t)ob*o_bs + (size_t)ot*o_rs + n] = v;
        } else {
          v = (v + bias[n])*(bng[n]*bnc) + bnb[n];
          v = lrelu(v);
          outH[(size_t)ob*o_bs + (size_t)ot*o_rs + n] = (f16)v;
        }
      }
}

// ---------------- cp head / cardiac params ----------------------------------
__global__ void __launch_bounds__(128) k_cp(const float* w1, const float* b1v, const float* lg,
                                            const float* lb, const float* w2, const float* b2v) {
  __shared__ float ft[512], av[128], s1[128], s2[128];
  int b = blockIdx.x, tid = threadIdx.x;
  for (int i = tid; i < 512; i += 128) ft[i] = g_feats[b*512 + i];
  __syncthreads();
  float acc = b1v[tid];
  for (int k = 0; k < 512; ++k) acc += w1[tid*512 + k]*ft[k];
  s1[tid] = acc; s2[tid] = acc*acc; __syncthreads();
  for (int s = 64; s > 0; s >>= 1) { if (tid < s) { s1[tid]+=s1[tid+s]; s2[tid]+=s2[tid+s]; } __syncthreads(); }
  float m = s1[0]*(1.0f/128.0f), var = s2[0]*(1.0f/128.0f) - m*m;
  av[tid] = lrelu((acc - m)*(1.0f/sqrtf(var + 1e-5f))*lg[tid] + lb[tid]);
  __syncthreads();
  if (tid < 4) {
    float s = b2v[tid];
    for (int i = 0; i < 128; ++i) s += w2[tid*128 + i]*av[i];
    g_cpar[b*4 + tid] = 1.0f/(1.0f + expf(-s));
  }
}

// ---------------- conv3 + enhanced ------------------------------------------
__global__ void __launch_bounds__(256) k_enh(const float* w3, const float* b3) {
  int idx = blockIdx.x*256 + threadIdx.x;
  int b = idx >> 10, t = idx & 1023;
  const f16* xc = g_c3in + (size_t)idx*128u;
  bool hm = (t > 0), hp = (t < 1023);
  float pre = b3[0];
  for (int c = 0; c < 128; ++c) {
    float xm = hm ? (float)xc[c - 128] : 0.0f;
    float x0 = (float)xc[c];
    float xp = hp ? (float)xc[c + 128] : 0.0f;
    pre += xm*w3[c*3] + x0*w3[c*3 + 1] + xp*w3[c*3 + 2];
  }
  float base = tanhf(pre);
  float cp0 = g_cpar[b*4 + 0], cp1 = g_cpar[b*4 + 1], cp2 = g_cpar[b*4 + 2], cp3 = g_cpar[b*4 + 3];
  float freq  = 0.19f + 0.1f*cp0;
  float amp   = 1.0f + 2.0f*cp1;
  float phase = 6.2831853071795864f*cp2;
  float basel = -0.5f + cp3;
  float tl = t*(1.0f/1023.0f);
  float arg = ((6.2831853071795864f*freq)*1024.0f)*tl + phase;
  float card = amp*sinf(arg) + basel;
  g_enh[idx] = 0.1f*base + 0.1f*g_osc[idx] + 0.7f*card + 0.1f*g_smean[t];
}

__global__ void __launch_bounds__(256) k_out(const int* labels, const float* sw,
                                             const float* aw, const float* ab, float* out) {
  int idx = blockIdx.x*256 + threadIdx.x;
  int b = idx >> 10, t = idx & 1023;
  int lab = labels[b];
  float e = g_enh[idx], r;
  if (lab == 1) r = e;
  else if (lab == 2) r = sw[0]*e;
  else if (lab == 3) {
    float em = (t > 0)    ? g_enh[idx - 1] : 0.0f;
    float ep = (t < 1023) ? g_enh[idx + 1] : 0.0f;
    r = aw[0]*em + aw[1]*e + aw[2]*ep + ab[0];
  } else r = 0.0f;
  out[idx] = r;
}

// ---------------- launch -----------------------------------------------------
extern "C" void kernel_launch(void* const* d_in, const int* in_sizes, int n_in,
                              void* d_out, int out_size, void* d_ws, size_t ws_size,
                              hipStream_t stream) {
  const float* z       = (const float*)d_in[0];
  const int*   labels  = (const int*)  d_in[1];
  const float* emb     = (const float*)d_in[2];
  const float* np_w    = (const float*)d_in[3];
  const float* np_b    = (const float*)d_in[4];
  const float* np_ln_g = (const float*)d_in[5];
  const float* np_ln_b = (const float*)d_in[6];
  const float* c_wih   = (const float*)d_in[7];
  const float* c_whh   = (const float*)d_in[8];
  const float* c_bih   = (const float*)d_in[9];
  const float* c_bhh   = (const float*)d_in[10];
  const float* f0_wih  = (const float*)d_in[11];
  const float* f0_whh  = (const float*)d_in[12];
  const float* f0_bih  = (const float*)d_in[13];
  const float* f0_bhh  = (const float*)d_in[14];
  const float* f_wih   = (const float*)d_in[15];
  const float* f_whh   = (const float*)d_in[16];
  const float* f_bih   = (const float*)d_in[17];
  const float* f_bhh   = (const float*)d_in[18];
  const float* osc_w1  = (const float*)d_in[19];
  const float* osc_b1  = (const float*)d_in[20];
  const float* osc_ln_g= (const float*)d_in[21];
  const float* osc_ln_b= (const float*)d_in[22];
  const float* osc_w2  = (const float*)d_in[23];
  const float* osc_b2  = (const float*)d_in[24];
  const float* cp_w1   = (const float*)d_in[25];
  const float* cp_b1   = (const float*)d_in[26];
  const float* cp_ln_g = (const float*)d_in[27];
  const float* cp_ln_b = (const float*)d_in[28];
  const float* cp_w2   = (const float*)d_in[29];
  const float* cp_b2   = (const float*)d_in[30];
  const float* sin_w   = (const float*)d_in[31];
  const float* sin_b   = (const float*)d_in[32];
  const float* conv1_w = (const float*)d_in[33];
  const float* conv1_b = (const float*)d_in[34];
  const float* bn1_g   = (const float*)d_in[35];
  const float* bn1_b   = (const float*)d_in[36];
  const float* conv2_w = (const float*)d_in[37];
  const float* conv2_b = (const float*)d_in[38];
  const float* bn2_g   = (const float*)d_in[39];
  const float* bn2_b   = (const float*)d_in[40];
  const float* conv3_w = (const float*)d_in[41];
  const float* conv3_b = (const float*)d_in[42];
  const float* stress_w= (const float*)d_in[43];
  const float* amuse_w = (const float*)d_in[44];
  const float* amuse_b = (const float*)d_in[45];
  float* out = (float*)d_out;

  k_prep_whh<<<5120, 256, 0, stream>>>(c_whh, f0_whh, f_whh);
  k_prep_wih<<<3072, 256, 0, stream>>>(f_wih, f_bih, f_bhh);
  k_prep_c1 <<<2560, 256, 0, stream>>>(conv1_w);
  k_prep_c2 <<< 384, 256, 0, stream>>>(conv2_w);
  k_zero    <<< 640, 256, 0, stream>>>();
  k_setup1  <<<  64, 256, 0, stream>>>(z, labels, emb, np_w, np_b, np_ln_g, np_ln_b);
  k_xg0     <<< 128,1024, 0, stream>>>(c_wih, c_bih, c_bhh, f0_wih, f0_bih, f0_bhh);
  k_osc     <<<  64, 256, 0, stream>>>(osc_w1, osc_b1, osc_ln_g, osc_ln_b, osc_w2, osc_b2);
  k_sinmean <<<   4, 256, 0, stream>>>(sin_w, sin_b);

  k_lstmA   <<<  64, 256, 0, stream>>>();                       // coarse + f0 concurrently
  for (int l = 0; l < 3; ++l) {                                 // f1, f2, f3
    int which = (l == 1) ? 1 : 0;                               // input seq ping-pong
    k_gemm  <<<dim3(512,16), 256, 0, stream>>>(which, l, nullptr, nullptr, nullptr);
    k_lstmF <<<  32, 256, 0, stream>>>(l);
  }
  k_cp      <<<  64, 128, 0, stream>>>(cp_w1, cp_b1, cp_ln_g, cp_ln_b, cp_w2, cp_b2);
  k_gemm    <<<dim3(512, 4), 256, 0, stream>>>(2, 0, conv1_b, bn1_g, bn1_b);   // conv1
  k_gemm    <<<dim3(512, 2), 256, 0, stream>>>(3, 0, conv2_b, bn2_g, bn2_b);   // conv2
  k_enh     <<< 256, 256, 0, stream>>>(conv3_w, conv3_b);
  k_out     <<< 256, 256, 0, stream>>>(labels, stress_w, amuse_w, amuse_b, out);
}

// Round 4
// 32412.537 us; speedup vs baseline: 2.1262x; 2.0095x over previous
//
#include <hip/hip_runtime.h>

typedef _Float16 f16;
typedef _Float16 f16x2 __attribute__((ext_vector_type(2)));
typedef _Float16 f16x8 __attribute__((ext_vector_type(8)));
typedef float    f32x4 __attribute__((ext_vector_type(4)));

// ---------------- static device scratch (avoids ws_size assumptions) --------
__device__ f16   g_Xpad [64u*1028u*512u];   // conv1 input (B,T+4,512): ch0-255 coarse, 256-511 fine(final)
__device__ f16   g_fseqA[64u*1024u*256u];   // fine sequence ping
__device__ f16   g_fseqB[64u*1024u*256u];   // fine sequence pong
__device__ float g_xg32 [64u*1024u*1024u];  // per-f-layer input projection, permuted gate order, fp32
__device__ f16   g_c2in [64u*1026u*256u];   // conv2 input (B,T+2,256), padded
__device__ f16   g_c3in [64u*1024u*128u];   // conv3 input (B,T,128)
// whh chunked layout: [L][kb:8][(q*4+j8)*256 + u][kl:8]; k = kb*32+j8*8+kl, gate row = q*256+u
__device__ f16   g_whhT2[5u*262144u];
__device__ f16   g_wihB [3u*262144u];       // [l][g'][k] fp16, permuted gate rows (g' = u*4+q)
__device__ float g_biasP[3*1024];           // permuted bih+bhh for f1..f3
__device__ f16   g_B1   [256u*2560u];       // conv1 weight as GEMM B [oc][r*512+ic]
__device__ f16   g_B2   [128u*768u];        // conv2 weight as GEMM B [oc][r*256+ic]
__device__ float g_xg0  [2*64*1024];        // static xg for coarse/f0, permuted [u*4+q]
__device__ float g_cat512[64*512];          // [h, le]
__device__ float g_h    [64*256];
__device__ float g_feats[64*512];           // [coarse.mean, fine.mean]
__device__ float g_osc  [64*1024];
__device__ float g_smean[1024];
__device__ float g_cpar [64*4];             // raw cp sigmoid outputs
__device__ float g_enh  [64*1024];

// ---------------- helpers ---------------------------------------------------
__device__ inline float fdot2f(f16x2 a, f16x2 b, float c) {
#if __has_builtin(__builtin_amdgcn_fdot2)
  return __builtin_amdgcn_fdot2(a, b, c, false);
#else
  return c + (float)a[0]*(float)b[0] + (float)a[1]*(float)b[1];
#endif
}
__device__ inline float sigm_fast(float x) { return 1.0f / (1.0f + __expf(-x)); }
__device__ inline float tanh_fast(float x) { float e = __expf(2.0f*x); return 1.0f - 2.0f/(e + 1.0f); }
__device__ inline float lrelu(float x) { return x < 0.0f ? 0.2f*x : x; }
__device__ inline void expand8(f16x8 v, f16x2* dst) {
  dst[0] = __builtin_shufflevector(v, v, 0, 1);
  dst[1] = __builtin_shufflevector(v, v, 2, 3);
  dst[2] = __builtin_shufflevector(v, v, 4, 5);
  dst[3] = __builtin_shufflevector(v, v, 6, 7);
}
__device__ __forceinline__ void dot8(f16x8 wv, const f16x2* hp, float& a) {
  a = fdot2f(__builtin_shufflevector(wv, wv, 0, 1), hp[0], a);
  a = fdot2f(__builtin_shufflevector(wv, wv, 2, 3), hp[1], a);
  a = fdot2f(__builtin_shufflevector(wv, wv, 4, 5), hp[2], a);
  a = fdot2f(__builtin_shufflevector(wv, wv, 6, 7), hp[3], a);
}

// Full 256-k dot for all 4 gates of unit t.
// wreg: chunks kb=0..3 (k in [0,128)) resident in VGPRs (64 octets, const-indexed).
// wlds: chunks kb=6..7 (k in [192,256)) resident in LDS (128 KB).
// wt:   per-thread global base; chunks kb=4..5 streamed as 32 plain 16B loads,
//       interleaved with resident compute to hide L2 latency.
__device__ __forceinline__ void lstm_dots(const f16x8* wreg, const f16* wlds,
                                          const f16* wt, const f16* hb, int t,
                                          float acc[4]) {
  f16x8 svA[16];
#pragma unroll
  for (int qj = 0; qj < 16; ++qj) svA[qj] = *(const f16x8*)(wt + (size_t)(64 + qj)*2048u);
  // register chunks kb=0..3
#pragma unroll
  for (int kb = 0; kb < 4; ++kb) {
    f16x2 hp[16];
#pragma unroll
    for (int j = 0; j < 4; ++j) expand8(*(const f16x8*)(hb + kb*32 + j*8), &hp[j*4]);
#pragma unroll
    for (int qj = 0; qj < 16; ++qj) dot8(wreg[kb*16 + qj], &hp[(qj & 3)*4], acc[qj >> 2]);
  }
  f16x8 svB[16];
#pragma unroll
  for (int qj = 0; qj < 16; ++qj) svB[qj] = *(const f16x8*)(wt + (size_t)(80 + qj)*2048u);
  // consume streamed kb=4
  {
    f16x2 hp[16];
#pragma unroll
    for (int j = 0; j < 4; ++j) expand8(*(const f16x8*)(hb + 4*32 + j*8), &hp[j*4]);
#pragma unroll
    for (int qj = 0; qj < 16; ++qj) dot8(svA[qj], &hp[(qj & 3)*4], acc[qj >> 2]);
  }
  // LDS chunks kb=6,7
#pragma unroll
  for (int kc = 0; kc < 2; ++kc) {
    f16x2 hp[16];
#pragma unroll
    for (int j = 0; j < 4; ++j) expand8(*(const f16x8*)(hb + (6 + kc)*32 + j*8), &hp[j*4]);
#pragma unroll
    for (int qj = 0; qj < 16; ++qj) {
      f16x8 wv = *(const f16x8*)(wlds + (size_t)((kc*16 + qj)*256 + t)*8u);
      dot8(wv, &hp[(qj & 3)*4], acc[qj >> 2]);
    }
  }
  // consume streamed kb=5
  {
    f16x2 hp[16];
#pragma unroll
    for (int j = 0; j < 4; ++j) expand8(*(const f16x8*)(hb + 5*32 + j*8), &hp[j*4]);
#pragma unroll
    for (int qj = 0; qj < 16; ++qj) dot8(svB[qj], &hp[(qj & 3)*4], acc[qj >> 2]);
  }
}

// ---------------- weight prep ----------------------------------------------
__global__ void __launch_bounds__(256) k_prep_whh(const float* cw, const float* f0w, const float* fw) {
  int bid = blockIdx.x;               // 5*1024
  int L = bid >> 10, g = bid & 1023, k = threadIdx.x;
  const float* src = (L == 0) ? cw : (L == 1) ? f0w : (fw + (size_t)(L-2)*262144u);
  int q = g >> 8, u = g & 255;                  // gate, unit
  int kb = k >> 5, j8 = (k >> 3) & 3, kl = k & 7;
  float v = src[(size_t)g*256 + k];
  g_whhT2[(size_t)L*262144u + (size_t)kb*32768u + (size_t)((q*4 + j8)*256 + u)*8u + kl] = (f16)v;
}
__global__ void __launch_bounds__(256) k_prep_wih(const float* fwih, const float* fbih, const float* fbhh) {
  int bid = blockIdx.x;               // 3*1024
  int L = bid >> 10, gp = bid & 1023, k = threadIdx.x;
  int j = gp >> 2, q = gp & 3, g = q*256 + j;
  g_wihB[(size_t)L*262144u + (size_t)gp*256u + k] = (f16)fwih[(size_t)L*262144u + (size_t)g*256u + k];
  if (k == 0) g_biasP[L*1024 + gp] = fbih[L*1024 + g] + fbhh[L*1024 + g];
}
__global__ void __launch_bounds__(256) k_prep_c1(const float* w) {
  int idx = blockIdx.x*256 + threadIdx.x;        // 655360
  int oc = idx / 2560, rem = idx % 2560, r = rem / 512, ic = rem % 512;
  g_B1[idx] = (f16)w[(size_t)oc*2560 + (size_t)ic*5 + r];
}
__global__ void __launch_bounds__(256) k_prep_c2(const float* w) {
  int idx = blockIdx.x*256 + threadIdx.x;        // 98304
  int oc = idx / 768, rem = idx % 768, r = rem / 256, ic = rem % 256;
  g_B2[idx] = (f16)w[(size_t)oc*768 + (size_t)ic*3 + r];
}
__global__ void __launch_bounds__(256) k_zero() {
  int idx = blockIdx.x*256 + threadIdx.x;        // 163840
  if (idx < 131072) {   // Xpad pad rows 0,1,1026,1027
    int b = idx >> 11, rem = idx & 2047, rr = rem >> 9, c = rem & 511;
    int row = (rr < 2) ? rr : 1024 + rr;
    g_Xpad[(size_t)b*526336u + (size_t)row*512u + c] = (f16)0.0f;
  } else {              // c2in pad rows 0, 1025
    int i2 = idx - 131072;
    int b = i2 >> 9, rem = i2 & 511, rr = rem >> 8, c = rem & 255;
    int row = rr ? 1025 : 0;
    g_c2in[(size_t)b*262656u + (size_t)row*256u + c] = (f16)0.0f;
  }
}

// ---------------- small front-end ops ---------------------------------------
__global__ void __launch_bounds__(256) k_setup1(const float* z, const int* labels, const float* emb,
                                                const float* npw, const float* npb,
                                                const float* lg, const float* lb) {
  __shared__ float x[384];
  __shared__ float s1[256], s2[256];
  int b = blockIdx.x, tid = threadIdx.x;
  int lab = labels[b];
  for (int i = tid; i < 384; i += 256)
    x[i] = (i < 128) ? z[b*128 + i] : emb[lab*256 + (i - 128)];
  __syncthreads();
  float acc = npb[tid];
  for (int k = 0; k < 384; ++k) acc += npw[tid*384 + k]*x[k];
  s1[tid] = acc; s2[tid] = acc*acc; __syncthreads();
  for (int s = 128; s > 0; s >>= 1) { if (tid < s) { s1[tid]+=s1[tid+s]; s2[tid]+=s2[tid+s]; } __syncthreads(); }
  float m = s1[0]*(1.0f/256.0f), var = s2[0]*(1.0f/256.0f) - m*m;
  float hv = (acc - m)*(1.0f/sqrtf(var + 1e-5f))*lg[tid] + lb[tid];
  hv = lrelu(hv);
  g_h[b*256 + tid] = hv;
  g_cat512[b*512 + tid] = hv;
  g_cat512[b*512 + 256 + tid] = x[128 + tid];
}
__global__ void __launch_bounds__(1024) k_xg0(const float* cwih, const float* cbih, const float* cbhh,
                                              const float* fwih, const float* fbih, const float* fbhh) {
  int bid = blockIdx.x;               // 128 = layer*64+b
  int layer = bid >> 6, b = bid & 63;
  int gp = threadIdx.x, j = gp >> 2, q = gp & 3, g = q*256 + j;
  __shared__ float cat[512];
  if (gp < 512) cat[gp] = g_cat512[b*512 + gp];
  __syncthreads();
  const float* w = layer ? fwih : cwih;
  float acc = layer ? (fbih[g] + fbhh[g]) : (cbih[g] + cbhh[g]);
  for (int k = 0; k < 512; ++k) acc += w[(size_t)g*512 + k]*cat[k];
  g_xg0[(layer*64 + b)*1024 + gp] = acc;
}
__global__ void __launch_bounds__(256) k_osc(const float* w1, const float* b1v, const float* lg,
                                             const float* lb, const float* w2, const float* b2v) {
  __shared__ float hb[256], av[256], s1[256], s2[256];
  int b = blockIdx.x, tid = threadIdx.x;
  hb[tid] = g_h[b*256 + tid];
  __syncthreads();
  float acc = b1v[tid];
  for (int k = 0; k < 256; ++k) acc += w1[tid*256 + k]*hb[k];
  s1[tid] = acc; s2[tid] = acc*acc; __syncthreads();
  for (int s = 128; s > 0; s >>= 1) { if (tid < s) { s1[tid]+=s1[tid+s]; s2[tid]+=s2[tid+s]; } __syncthreads(); }
  float m = s1[0]*(1.0f/256.0f), var = s2[0]*(1.0f/256.0f) - m*m;
  av[tid] = lrelu((acc - m)*(1.0f/sqrtf(var + 1e-5f))*lg[tid] + lb[tid]);
  __syncthreads();
  for (int tt = tid; tt < 1024; tt += 256) {
    float o = b2v[tt];
    for (int i = 0; i < 256; ++i) o += w2[(size_t)tt*256 + i]*av[i];
    g_osc[b*1024 + tt] = tanhf(o);
  }
}
__global__ void __launch_bounds__(256) k_sinmean(const float* sw, const float* sb) {
  int tt = blockIdx.x*256 + threadIdx.x;   // grid 4
  const float F[6] = {0.19f, 0.21f, 0.23f, 0.25f, 0.27f, 0.29f};
  float tl = tt*(1.0f/1023.0f);
  float sc[12];
  for (int j = 0; j < 6; ++j) {
    float p = (6.2831853071795864f * tl) * F[j] * 1024.0f;
    sc[j] = sinf(p); sc[6 + j] = cosf(p);
  }
  float a = 0.0f;
  for (int i = 0; i < 128; ++i) {
    float s = sb[i];
    for (int j = 0; j < 12; ++j) s += sw[i*12 + j]*sc[j];
    a += s;
  }
  g_smean[tt] = a*(1.0f/128.0f);
}

// ---------------- LSTM core (G=1 batch / block, 256 threads) -----------------
// thread t owns hidden unit t; c stays in a register; weights resident:
// 256 VGPR (k 0..127) + 128 KB LDS (k 192..255); k 128..191 streamed from L2
// with step-invariant addresses. Plain loads/ds only (no DMA builtins);
// 1 barrier/step for the h exchange. LDS total = 129 KB/block -> 1 block/CU.
__global__ void __launch_bounds__(256, 1) k_lstmA() {
  int bid = blockIdx.x;              // 128: [0,64) coarse, [64,128) f0
  int layer = bid >> 6, b = bid & 63;
  int t = threadIdx.x;
  const f16* Wc = g_whhT2 + (size_t)layer*262144u;
  const f16* wt = Wc + t*8;
  __shared__ __align__(16) f16 wlds[65536];
  __shared__ __align__(16) f16 hbuf[2][256];
  f16x8 wreg[64];
#pragma unroll
  for (int s = 0; s < 64; ++s) wreg[s] = *(const f16x8*)(wt + (size_t)s*2048u);
#pragma unroll 8
  for (int s = 0; s < 32; ++s) {
    int e = (s*256 + t)*8;
    *(f16x8*)(wlds + e) = *(const f16x8*)(Wc + 196608 + e);
  }
  f32x4 xvA = *(const f32x4*)(g_xg0 + (layer*64 + b)*1024 + 4*t);
  hbuf[0][t] = (f16)0.0f;
  float c0 = 0.0f, sum0 = 0.0f;
  __syncthreads();
  f16* outp; int ostride;
  if (layer == 0) { outp = g_Xpad + (size_t)b*526336u + 1024 + t; ostride = 512; }
  else            { outp = g_fseqA + (size_t)b*262144u + t;       ostride = 256; }
  int cur = 0;
  for (int step = 0; step < 1024; ++step) {
    float acc[4] = {xvA[0], xvA[1], xvA[2], xvA[3]};
    const f16* hb = &hbuf[cur][0];
    lstm_dots(wreg, wlds, wt, hb, t, acc);
    float ii = sigm_fast(acc[0]), ff = sigm_fast(acc[1]);
    float gg = tanh_fast(acc[2]), oo = sigm_fast(acc[3]);
    c0 = ff*c0 + ii*gg;
    float h0 = oo*tanh_fast(c0); sum0 += h0;
    hbuf[cur ^ 1][t] = (f16)h0;
    outp[(size_t)step*ostride] = (f16)h0;
    __syncthreads();
    cur ^= 1;
  }
  if (layer == 0) g_feats[b*512 + t] = sum0*(1.0f/1024.0f);
}

__global__ void __launch_bounds__(256, 1) k_lstmF(int l) {   // l=0..2 -> fine layers f1..f3
  int b = blockIdx.x;               // 64
  int t = threadIdx.x;
  const f16* Wc = g_whhT2 + (size_t)(2 + l)*262144u;
  const f16* wt = Wc + t*8;
  __shared__ __align__(16) f16 wlds[65536];
  __shared__ __align__(16) f16 hbuf[2][256];
  f16x8 wreg[64];
#pragma unroll
  for (int s = 0; s < 64; ++s) wreg[s] = *(const f16x8*)(wt + (size_t)s*2048u);
#pragma unroll 8
  for (int s = 0; s < 32; ++s) {
    int e = (s*256 + t)*8;
    *(f16x8*)(wlds + e) = *(const f16x8*)(Wc + 196608 + e);
  }
  const f32x4* xp = (const f32x4*)(g_xg32 + (size_t)b*1048576u + 4*t);
  hbuf[0][t] = (f16)0.0f;
  float c0 = 0.0f, sum0 = 0.0f;
  __syncthreads();
  f16* outp; int ostride;
  if (l == 0)      { outp = g_fseqB + (size_t)b*262144u + t; ostride = 256; }
  else if (l == 1) { outp = g_fseqA + (size_t)b*262144u + t; ostride = 256; }
  else             { outp = g_Xpad + (size_t)b*526336u + 1024 + 256 + t; ostride = 512; }
  int cur = 0;
  for (int step = 0; step < 1024; ++step) {
    f32x4 xv = xp[(size_t)step*256u];
    float acc[4] = {0.0f, 0.0f, 0.0f, 0.0f};
    const f16* hb = &hbuf[cur][0];
    lstm_dots(wreg, wlds, wt, hb, t, acc);
    float ii = sigm_fast(acc[0] + xv[0]), ff = sigm_fast(acc[1] + xv[1]);
    float gg = tanh_fast(acc[2] + xv[2]), oo = sigm_fast(acc[3] + xv[3]);
    c0 = ff*c0 + ii*gg;
    float h0 = oo*tanh_fast(c0); sum0 += h0;
    hbuf[cur ^ 1][t] = (f16)h0;
    outp[(size_t)step*ostride] = (f16)h0;
    __syncthreads();
    cur ^= 1;
  }
  if (l == 2) g_feats[b*512 + 256 + t] = sum0*(1.0f/1024.0f);
}

// ---------------- generic fp16 MFMA GEMM (implicit conv / xg projection) ----
__global__ void __launch_bounds__(256) k_gemm(int which, int l,
                                              const float* cb, const float* bng, const float* bnb) {
  const f16* A; size_t a_bs; int a_rs, K, N; const f16* Bm; int mode;
  float* outF = nullptr; f16* outH = nullptr; size_t o_bs; int o_rs;
  const float* bias;
  if (which <= 1) {
    A = (which == 0) ? g_fseqA : g_fseqB; a_bs = 262144u; a_rs = 256; K = 256; N = 1024;
    Bm = g_wihB + (size_t)l*262144u; mode = 0; bias = g_biasP + l*1024;
    outF = g_xg32; o_bs = 1048576u; o_rs = 1024;
  } else if (which == 2) {
    A = g_Xpad; a_bs = 526336u; a_rs = 512; K = 2560; N = 256; Bm = g_B1; mode = 1; bias = cb;
    outH = g_c2in + 256; o_bs = 262656u; o_rs = 256;
  } else {
    A = g_c2in; a_bs = 262656u; a_rs = 256; K = 768; N = 128; Bm = g_B2; mode = 1; bias = cb;
    outH = g_c3in; o_bs = 131072u; o_rs = 128;
  }
  int tid = threadIdx.x, wave = tid >> 6, lane = tid & 63;
  int m0 = blockIdx.x*128, n0 = blockIdx.y*64;
  __shared__ __align__(16) f16 Asm[128*72];
  __shared__ __align__(16) f16 Bsm[64*72];
  f32x4 acc[2][4];
#pragma unroll
  for (int i = 0; i < 2; ++i)
#pragma unroll
    for (int j = 0; j < 4; ++j) { f32x4 zz = {0.f,0.f,0.f,0.f}; acc[i][j] = zz; }
  int ar = tid & 127, ac = (tid >> 7)*32;
  int mrow = m0 + ar, abb = mrow >> 10, att = mrow & 1023;
  const f16* aptr = A + (size_t)abb*a_bs + (size_t)att*a_rs + ac;
  int br = tid & 63, bc = (tid >> 6)*16;
  const f16* bptr = Bm + (size_t)(n0 + br)*K + bc;
  int nkb = K >> 6;
  for (int kb = 0; kb < nkb; ++kb) {
    f16x8 av0 = *(const f16x8*)(aptr + 0);
    f16x8 av1 = *(const f16x8*)(aptr + 8);
    f16x8 av2 = *(const f16x8*)(aptr + 16);
    f16x8 av3 = *(const f16x8*)(aptr + 24);
    f16x8 bv0 = *(const f16x8*)(bptr + 0);
    f16x8 bv1 = *(const f16x8*)(bptr + 8);
    aptr += 64; bptr += 64;
    __syncthreads();
    *(f16x8*)(&Asm[ar*72 + ac + 0])  = av0;
    *(f16x8*)(&Asm[ar*72 + ac + 8])  = av1;
    *(f16x8*)(&Asm[ar*72 + ac + 16]) = av2;
    *(f16x8*)(&Asm[ar*72 + ac + 24]) = av3;
    *(f16x8*)(&Bsm[br*72 + bc + 0])  = bv0;
    *(f16x8*)(&Bsm[br*72 + bc + 8])  = bv1;
    __syncthreads();
#pragma unroll
    for (int ks = 0; ks < 2; ++ks) {
      int ko = ks*32 + (lane >> 4)*8;
      f16x8 a0 = *(const f16x8*)(&Asm[(wave*32 + (lane & 15))*72 + ko]);
      f16x8 a1 = *(const f16x8*)(&Asm[(wave*32 + 16 + (lane & 15))*72 + ko]);
#pragma unroll
      for (int nt = 0; nt < 4; ++nt) {
        f16x8 bf = *(const f16x8*)(&Bsm[(nt*16 + (lane & 15))*72 + ko]);
        acc[0][nt] = __builtin_amdgcn_mfma_f32_16x16x32_f16(a0, bf, acc[0][nt], 0, 0, 0);
        acc[1][nt] = __builtin_amdgcn_mfma_f32_16x16x32_f16(a1, bf, acc[1][nt], 0, 0, 0);
      }
    }
  }
  const float bnc = 0.99999500003749969f;  // 1/sqrt(1+1e-5)
#pragma unroll
  for (int mt = 0; mt < 2; ++mt)
#pragma unroll
    for (int nt = 0; nt < 4; ++nt)
#pragma unroll
      for (int r = 0; r < 4; ++r) {
        int m_loc = wave*32 + mt*16 + (lane >> 4)*4 + r;
        int n = n0 + nt*16 + (lane & 15);
        int mg = m0 + m_loc, ob = mg >> 10, ot = mg & 1023;
        float v = acc[mt][nt][r];
        if (mode == 0) {
          v += bias[n];
          outF[(size_t)ob*o_bs + (size_t)ot*o_rs + n] = v;
        } else {
          v = (v + bias[n])*(bng[n]*bnc) + bnb[n];
          v = lrelu(v);
          outH[(size_t)ob*o_bs + (size_t)ot*o_rs + n] = (f16)v;
        }
      }
}

// ---------------- cp head / cardiac params ----------------------------------
__global__ void __launch_bounds__(128) k_cp(const float* w1, const float* b1v, const float* lg,
                                            const float* lb, const float* w2, const float* b2v) {
  __shared__ float ft[512], av[128], s1[128], s2[128];
  int b = blockIdx.x, tid = threadIdx.x;
  for (int i = tid; i < 512; i += 128) ft[i] = g_feats[b*512 + i];
  __syncthreads();
  float acc = b1v[tid];
  for (int k = 0; k < 512; ++k) acc += w1[tid*512 + k]*ft[k];
  s1[tid] = acc; s2[tid] = acc*acc; __syncthreads();
  for (int s = 64; s > 0; s >>= 1) { if (tid < s) { s1[tid]+=s1[tid+s]; s2[tid]+=s2[tid+s]; } __syncthreads(); }
  float m = s1[0]*(1.0f/128.0f), var = s2[0]*(1.0f/128.0f) - m*m;
  av[tid] = lrelu((acc - m)*(1.0f/sqrtf(var + 1e-5f))*lg[tid] + lb[tid]);
  __syncthreads();
  if (tid < 4) {
    float s = b2v[tid];
    for (int i = 0; i < 128; ++i) s += w2[tid*128 + i]*av[i];
    g_cpar[b*4 + tid] = 1.0f/(1.0f + expf(-s));
  }
}

// ---------------- conv3 + enhanced ------------------------------------------
__global__ void __launch_bounds__(256) k_enh(const float* w3, const float* b3) {
  int idx = blockIdx.x*256 + threadIdx.x;
  int b = idx >> 10, t = idx & 1023;
  const f16* xc = g_c3in + (size_t)idx*128u;
  bool hm = (t > 0), hp = (t < 1023);
  float pre = b3[0];
  for (int c = 0; c < 128; ++c) {
    float xm = hm ? (float)xc[c - 128] : 0.0f;
    float x0 = (float)xc[c];
    float xp = hp ? (float)xc[c + 128] : 0.0f;
    pre += xm*w3[c*3] + x0*w3[c*3 + 1] + xp*w3[c*3 + 2];
  }
  float base = tanhf(pre);
  float cp0 = g_cpar[b*4 + 0], cp1 = g_cpar[b*4 + 1], cp2 = g_cpar[b*4 + 2], cp3 = g_cpar[b*4 + 3];
  float freq  = 0.19f + 0.1f*cp0;
  float amp   = 1.0f + 2.0f*cp1;
  float phase = 6.2831853071795864f*cp2;
  float basel = -0.5f + cp3;
  float tl = t*(1.0f/1023.0f);
  float arg = ((6.2831853071795864f*freq)*1024.0f)*tl + phase;
  float card = amp*sinf(arg) + basel;
  g_enh[idx] = 0.1f*base + 0.1f*g_osc[idx] + 0.7f*card + 0.1f*g_smean[t];
}

__global__ void __launch_bounds__(256) k_out(const int* labels, const float* sw,
                                             const float* aw, const float* ab, float* out) {
  int idx = blockIdx.x*256 + threadIdx.x;
  int b = idx >> 10, t = idx & 1023;
  int lab = labels[b];
  float e = g_enh[idx], r;
  if (lab == 1) r = e;
  else if (lab == 2) r = sw[0]*e;
  else if (lab == 3) {
    float em = (t > 0)    ? g_enh[idx - 1] : 0.0f;
    float ep = (t < 1023) ? g_enh[idx + 1] : 0.0f;
    r = aw[0]*em + aw[1]*e + aw[2]*ep + ab[0];
  } else r = 0.0f;
  out[idx] = r;
}

// ---------------- launch -----------------------------------------------------
extern "C" void kernel_launch(void* const* d_in, const int* in_sizes, int n_in,
                              void* d_out, int out_size, void* d_ws, size_t ws_size,
                              hipStream_t stream) {
  const float* z       = (const float*)d_in[0];
  const int*   labels  = (const int*)  d_in[1];
  const float* emb     = (const float*)d_in[2];
  const float* np_w    = (const float*)d_in[3];
  const float* np_b    = (const float*)d_in[4];
  const float* np_ln_g = (const float*)d_in[5];
  const float* np_ln_b = (const float*)d_in[6];
  const float* c_wih   = (const float*)d_in[7];
  const float* c_whh   = (const float*)d_in[8];
  const float* c_bih   = (const float*)d_in[9];
  const float* c_bhh   = (const float*)d_in[10];
  const float* f0_wih  = (const float*)d_in[11];
  const float* f0_whh  = (const float*)d_in[12];
  const float* f0_bih  = (const float*)d_in[13];
  const float* f0_bhh  = (const float*)d_in[14];
  const float* f_wih   = (const float*)d_in[15];
  const float* f_whh   = (const float*)d_in[16];
  const float* f_bih   = (const float*)d_in[17];
  const float* f_bhh   = (const float*)d_in[18];
  const float* osc_w1  = (const float*)d_in[19];
  const float* osc_b1  = (const float*)d_in[20];
  const float* osc_ln_g= (const float*)d_in[21];
  const float* osc_ln_b= (const float*)d_in[22];
  const float* osc_w2  = (const float*)d_in[23];
  const float* osc_b2  = (const float*)d_in[24];
  const float* cp_w1   = (const float*)d_in[25];
  const float* cp_b1   = (const float*)d_in[26];
  const float* cp_ln_g = (const float*)d_in[27];
  const float* cp_ln_b = (const float*)d_in[28];
  const float* cp_w2   = (const float*)d_in[29];
  const float* cp_b2   = (const float*)d_in[30];
  const float* sin_w   = (const float*)d_in[31];
  const float* sin_b   = (const float*)d_in[32];
  const float* conv1_w = (const float*)d_in[33];
  const float* conv1_b = (const float*)d_in[34];
  const float* bn1_g   = (const float*)d_in[35];
  const float* bn1_b   = (const float*)d_in[36];
  const float* conv2_w = (const float*)d_in[37];
  const float* conv2_b = (const float*)d_in[38];
  const float* bn2_g   = (const float*)d_in[39];
  const float* bn2_b   = (const float*)d_in[40];
  const float* conv3_w = (const float*)d_in[41];
  const float* conv3_b = (const float*)d_in[42];
  const float* stress_w= (const float*)d_in[43];
  const float* amuse_w = (const float*)d_in[44];
  const float* amuse_b = (const float*)d_in[45];
  float* out = (float*)d_out;

  k_prep_whh<<<5120, 256, 0, stream>>>(c_whh, f0_whh, f_whh);
  k_prep_wih<<<3072, 256, 0, stream>>>(f_wih, f_bih, f_bhh);
  k_prep_c1 <<<2560, 256, 0, stream>>>(conv1_w);
  k_prep_c2 <<< 384, 256, 0, stream>>>(conv2_w);
  k_zero    <<< 640, 256, 0, stream>>>();
  k_setup1  <<<  64, 256, 0, stream>>>(z, labels, emb, np_w, np_b, np_ln_g, np_ln_b);
  k_xg0     <<< 128,1024, 0, stream>>>(c_wih, c_bih, c_bhh, f0_wih, f0_bih, f0_bhh);
  k_osc     <<<  64, 256, 0, stream>>>(osc_w1, osc_b1, osc_ln_g, osc_ln_b, osc_w2, osc_b2);
  k_sinmean <<<   4, 256, 0, stream>>>(sin_w, sin_b);

  k_lstmA   <<< 128, 256, 0, stream>>>();                       // coarse + f0 concurrently
  for (int l = 0; l < 3; ++l) {                                 // f1, f2, f3
    int which = (l == 1) ? 1 : 0;                               // input seq ping-pong
    k_gemm  <<<dim3(512,16), 256, 0, stream>>>(which, l, nullptr, nullptr, nullptr);
    k_lstmF <<<  64, 256, 0, stream>>>(l);
  }
  k_cp      <<<  64, 128, 0, stream>>>(cp_w1, cp_b1, cp_ln_g, cp_ln_b, cp_w2, cp_b2);
  k_gemm    <<<dim3(512, 4), 256, 0, stream>>>(2, 0, conv1_b, bn1_g, bn1_b);   // conv1
  k_gemm    <<<dim3(512, 2), 256, 0, stream>>>(3, 0, conv2_b, bn2_g, bn2_b);   // conv2
  k_enh     <<< 256, 256, 0, stream>>>(conv3_w, conv3_b);
  k_out     <<< 256, 256, 0, stream>>>(labels, stress_w, amuse_w, amuse_b, out);
}